// Round 1
// baseline (600.549 us; speedup 1.0000x reference)
//
#include <hip/hip_runtime.h>
#include <cstdint>
#include <cstddef>

// ---------------------------------------------------------------------------
// DynaResidualBlock: hypernet GEMM (MFMA, hi/lo bf16 split = fp32-accurate)
//  -> per-sample 1x1 conv chain (bf16 MFMA)
//   FIN=64 FOUT=64 FH=128 LAT=512  B=16  H*W=16384
//   sizes = [8192,16384,16384,8192,4096,128,128,128,64,64], KTOT=53760
// ---------------------------------------------------------------------------

typedef short bf16x8 __attribute__((ext_vector_type(8)));   // 8 bf16 = 4 VGPRs
typedef float f32x4  __attribute__((ext_vector_type(4)));
typedef float f32x16 __attribute__((ext_vector_type(16)));  // MFMA 32x32 acc

#define DEVFN static __device__ __forceinline__

constexpr int WELEM      = 53248;           // bf16 weight elements per sample
constexpr size_t WS_WSHORTS = (size_t)WELEM;
constexpr size_t WS_WBYTES_TOT = (size_t)16 * WELEM * 2;     // 1,703,936
constexpr size_t WS_BOFF  = WS_WBYTES_TOT;                   // b_ws: 16*512 f32
constexpr size_t WS_AHOFF = WS_BOFF + 16 * 512 * 4;          // ah frags: 16 KB
constexpr size_t WS_ALOFF = WS_AHOFF + 16384;                // al frags: 16 KB

DEVFN unsigned bf16rne(float f) {
  unsigned u = __builtin_bit_cast(unsigned, f);
  return (u + 0x7fffu + ((u >> 16) & 1u)) >> 16;
}
DEVFN unsigned pk2(float lo, float hi) {
  return bf16rne(lo) | (bf16rne(hi) << 16);
}

// ---------------------------------------------------------------------------
// Kernel 0: lat -> hi/lo bf16 A-frags for mfma_16x16x32.
// frag element (s, lane l, j): A[m=l&15][k = s*32 + (l>>4)*8 + j]
// stored at ah_ws[(s*64+l)*8 + j]. 1024 (s,l) pairs.
// ---------------------------------------------------------------------------
__global__ __launch_bounds__(256) void lat_prep(
    const float* __restrict__ lat, unsigned short* __restrict__ ah_ws,
    unsigned short* __restrict__ al_ws) {
  const int id = blockIdx.x * 256 + threadIdx.x;  // 0..1023
  const int s = id >> 6, l = id & 63;
  const int m = l & 15, q = l >> 4;
  const float* ap = lat + m * 512 + s * 32 + q * 8;
  float f[8];
#pragma unroll
  for (int j = 0; j < 8; ++j) f[j] = ap[j];
  unsigned H[4], L[4];
#pragma unroll
  for (int p = 0; p < 4; ++p) {
    const unsigned u0 = __builtin_bit_cast(unsigned, f[2 * p]);
    const unsigned u1 = __builtin_bit_cast(unsigned, f[2 * p + 1]);
    const unsigned h0 = u0 & 0xFFFF0000u, h1 = u1 & 0xFFFF0000u;
    H[p] = (h0 >> 16) | h1;
    const float lo0 = f[2 * p] - __builtin_bit_cast(float, h0);
    const float lo1 = f[2 * p + 1] - __builtin_bit_cast(float, h1);
    L[p] = pk2(lo0, lo1);
  }
  *(uint4*)&ah_ws[(size_t)(s * 64 + l) * 8] = make_uint4(H[0], H[1], H[2], H[3]);
  *(uint4*)&al_ws[(size_t)(s * 64 + l) * 8] = make_uint4(L[0], L[1], L[2], L[3]);
}

// ---------------------------------------------------------------------------
// Kernel 1: ks = lat @ W.T + bias via MFMA 16x16x32 (hi/lo split, 3 mfma/step)
// One 16-column tile per wave; 3360 tiles = 840 blocks x 4 waves.
// Wave streams its 16 W rows (columns of ks) with an 8-step float4 ring
// (16 KB in flight per wave). Epilogue scatters to frag-layout bf16 ws.
// ---------------------------------------------------------------------------
#define MFMA16(A, B, C) __builtin_amdgcn_mfma_f32_16x16x32_bf16((A), (B), (C), 0, 0, 0)

__global__ __launch_bounds__(256, 2) void hyper_gemm(
    const float* __restrict__ W, const float* __restrict__ bias,
    const unsigned short* __restrict__ ah_ws,
    const unsigned short* __restrict__ al_ws,
    unsigned short* __restrict__ w_ws, float* __restrict__ b_ws) {
  const int tid = threadIdx.x;
  const int wv = tid >> 6;
  const int l = tid & 63;
  const int q = l >> 4;
  const int g = blockIdx.x * 4 + wv;  // tile id 0..3359
  const int n0 = g * 16;
  const int n = n0 + (l & 15);

  // A frags (shared by all waves; L2-hot)
  bf16x8 Ah[16], Al[16];
#pragma unroll
  for (int s = 0; s < 16; ++s) {
    Ah[s] = *(const bf16x8*)&ah_ws[(size_t)(s * 64 + l) * 8];
    Al[s] = *(const bf16x8*)&al_ws[(size_t)(s * 64 + l) * 8];
  }

  // B stream: lane reads W[n][s*32 + q*8 .. +8]
  const float* bp = W + (size_t)n * 512 + q * 8;
  float4 ld[8][2];
#pragma unroll
  for (int s = 0; s < 8; ++s) {
    ld[s][0] = *(const float4*)(bp + s * 32);
    ld[s][1] = *(const float4*)(bp + s * 32 + 4);
  }

  f32x4 acc = {0.f, 0.f, 0.f, 0.f};
#pragma unroll
  for (int s = 0; s < 16; ++s) {
    const float4 b0 = ld[s & 7][0];
    const float4 b1 = ld[s & 7][1];
    if (s < 8) {
      ld[s][0] = *(const float4*)(bp + (s + 8) * 32);
      ld[s][1] = *(const float4*)(bp + (s + 8) * 32 + 4);
    }
    const float f[8] = {b0.x, b0.y, b0.z, b0.w, b1.x, b1.y, b1.z, b1.w};
    union { unsigned u[4]; bf16x8 v; } BH, BL;
#pragma unroll
    for (int p = 0; p < 4; ++p) {
      const unsigned u0 = __builtin_bit_cast(unsigned, f[2 * p]);
      const unsigned u1 = __builtin_bit_cast(unsigned, f[2 * p + 1]);
      const unsigned h0 = u0 & 0xFFFF0000u, h1 = u1 & 0xFFFF0000u;
      BH.u[p] = (h0 >> 16) | h1;
      const float lo0 = f[2 * p] - __builtin_bit_cast(float, h0);
      const float lo1 = f[2 * p + 1] - __builtin_bit_cast(float, h1);
      BL.u[p] = pk2(lo0, lo1);
    }
    acc = MFMA16(Ah[s], BH.v, acc);
    acc = MFMA16(Ah[s], BL.v, acc);
    acc = MFMA16(Al[s], BH.v, acc);
  }

  // epilogue: lane holds column n, samples b = q*4 + r  (D: col=l&15, row=q*4+r)
  const float bv = bias[n];
  if (n0 >= 53248) {  // conv biases: fp32, per-sample contiguous [512]
    const int j = n - 53248;
#pragma unroll
    for (int r = 0; r < 4; ++r) b_ws[(q * 4 + r) * 512 + j] = acc[r] + bv;
    return;
  }
  int fragbase, off, kbits;
  float scale;
  if (n < 8192)       { fragbase = 0;  off = 0;     kbits = 6; scale = 0.08838834764831845f; }
  else if (n < 24576) { fragbase = 16; off = 8192;  kbits = 7; scale = 0.08838834764831845f; }
  else if (n < 40960) { fragbase = 48; off = 24576; kbits = 7; scale = 0.08838834764831845f; }
  else if (n < 49152) { fragbase = 80; off = 40960; kbits = 7; scale = 0.125f; }
  else                { fragbase = 96; off = 49152; kbits = 6; scale = 0.125f; }
  const int r0 = n - off;
  const int m = r0 >> kbits;
  const int k = r0 & ((1 << kbits) - 1);
  const int mt = m >> 5, ks = k >> 4;
  const int lane = (m & 31) + 32 * ((k >> 3) & 1);
  const int j = k & 7;
  const int frag = fragbase + mt * (1 << (kbits - 4)) + ks;
  const size_t eoff = (size_t)frag * 512 + lane * 8 + j;  // in shorts
#pragma unroll
  for (int r = 0; r < 4; ++r) {
    const float v = (acc[r] + bv) * scale;
    w_ws[(size_t)(q * 4 + r) * WS_WSHORTS + eoff] = (unsigned short)bf16rne(v);
  }
}

// ---------------------------------------------------------------------------
// Kernel 2: per-sample conv chain, v2.
// 256 blocks (sample = blk>>4, chunk = blk&15), 8 waves (512 thr), each wave
// owns 64 pixels/iter, 2 iters (1024 px per block). ALL weight A-frags staged
// in LDS (104 frags = 106.5 KB -> 1 block/CU, 2 waves/SIMD). h handoff between
// stages is fully in-register: C-frag acc -> pk2 bf16 pairs ->
// permlane32_swap half-exchange -> B-frags (no LDS round trip, no bank
// conflicts, no per-wave h buffer).
//   C layout (32x32): col=l&31, row=(reg&3)+8*(reg>>2)+4*(l>>5)
//   B layout (32x32x16): n=l&31, k=8*(l>>5)+j
//   => channel c5=8G+t lives at (lh=t>>2, reg=4G+(t&3)); with
//      P[G][w]=pk2(acc[4G+2w],acc[4G+2w+1]),
//      r = permlane32_swap(P[2e][w], P[2e+1][w]) gives
//      r[0]={a.lo,b.lo} = B word j=(2w,2w+1), r[1]={a.hi,b.hi} = j=(2w+4,2w+5)
//      of frag ks=2*mt+e  (verified against the m214-v22 T12 derivation and
//      the previous harness-passing LDS write_h mapping).
// x loads for iter it+1 issued at OUT-stage start so the 64 xr float regs do
// not overlap the MIDA/MIDB register-liveness peak (h_in 64 + h_out 48 + acc).
// ---------------------------------------------------------------------------

DEVFN f32x16 bias_init(const float* bl, int mt, int lh) {
  f32x16 a;
#pragma unroll
  for (int g = 0; g < 4; ++g) {
    const float4 bv = *(const float4*)&bl[mt * 32 + 8 * g + 4 * lh];
    a[4 * g + 0] = bv.x; a[4 * g + 1] = bv.y;
    a[4 * g + 2] = bv.z; a[4 * g + 3] = bv.w;
  }
  return a;
}

// acc (nt=0,nt=1) of output-channel tile mt -> relu -> 4 B-frags into
// h[(2*mt+e)*2 + nt]  (frag ks=2*mt+e covers channels 16ks..16ks+15)
DEVFN void acc_to_bfrags(const f32x16& a0, const f32x16& a1, bf16x8* h, int mt) {
  unsigned P0[4][2], P1[4][2];  // [G][w]
#pragma unroll
  for (int g = 0; g < 4; ++g) {
    P0[g][0] = pk2(fmaxf(a0[4 * g + 0], 0.f), fmaxf(a0[4 * g + 1], 0.f));
    P0[g][1] = pk2(fmaxf(a0[4 * g + 2], 0.f), fmaxf(a0[4 * g + 3], 0.f));
    P1[g][0] = pk2(fmaxf(a1[4 * g + 0], 0.f), fmaxf(a1[4 * g + 1], 0.f));
    P1[g][1] = pk2(fmaxf(a1[4 * g + 2], 0.f), fmaxf(a1[4 * g + 3], 0.f));
  }
#pragma unroll
  for (int e = 0; e < 2; ++e) {
    auto r0 = __builtin_amdgcn_permlane32_swap(P0[2 * e][0], P0[2 * e + 1][0], false, false);
    auto r1 = __builtin_amdgcn_permlane32_swap(P0[2 * e][1], P0[2 * e + 1][1], false, false);
    union { unsigned u[4]; bf16x8 v; } F0;
    F0.u[0] = r0[0]; F0.u[1] = r1[0]; F0.u[2] = r0[1]; F0.u[3] = r1[1];
    h[(2 * mt + e) * 2 + 0] = F0.v;
    auto q0 = __builtin_amdgcn_permlane32_swap(P1[2 * e][0], P1[2 * e + 1][0], false, false);
    auto q1 = __builtin_amdgcn_permlane32_swap(P1[2 * e][1], P1[2 * e + 1][1], false, false);
    union { unsigned u[4]; bf16x8 v; } F1;
    F1.u[0] = q0[0]; F1.u[1] = q1[0]; F1.u[2] = q0[1]; F1.u[3] = q1[1];
    h[(2 * mt + e) * 2 + 1] = F1.v;
  }
}

#define MFMA32(A, B, C) __builtin_amdgcn_mfma_f32_32x32x16_bf16((A), (B), (C), 0, 0, 0)

__global__ __launch_bounds__(512, 2) void dyn_conv(
    const float* __restrict__ x, const unsigned short* __restrict__ w_ws,
    const float* __restrict__ b_ws, float* __restrict__ out) {
  // LDS frag order = w_ws layout: in[0..16) mida[16..48) midb[48..80)
  //                               out[80..96) short[96..104)
  __shared__ short wl[104 * 512];  // 106496 B
  __shared__ float bl[512];        //   2048 B

  const int s = blockIdx.x >> 4;
  const int chunk = blockIdx.x & 15;
  const int tid = threadIdx.x;
  const int wv = tid >> 6;       // 0..7
  const int l = tid & 63;
  const int l31 = l & 31;
  const int lh = l >> 5;

  const unsigned short* wbase = w_ws + (size_t)s * WS_WSHORTS;
  const float* xbase = x + (size_t)(s * 64) * 16384;

  float xr[2][4][8];
  auto load_xr = [&](int it2) {
    const int px0 = chunk * 1024 + it2 * 512 + wv * 64;
#pragma unroll
    for (int nt = 0; nt < 2; ++nt) {
#pragma unroll
      for (int ks = 0; ks < 4; ++ks) {
        const float* xp =
            xbase + (size_t)(ks * 16 + lh * 8) * 16384 + px0 + nt * 32 + l31;
#pragma unroll
        for (int j = 0; j < 8; ++j) xr[nt][ks][j] = xp[(size_t)j * 16384];
      }
    }
  };
  // iter-0 x loads first: HBM latency overlaps the weight staging below
  load_xr(0);

  // stage ALL weights -> LDS (w_ws frag layout is contiguous; copy verbatim)
  for (int f = wv; f < 104; f += 8)
    *(int4*)&wl[f * 512 + l * 8] = *(const int4*)&wbase[(size_t)f * 512 + l * 8];
  bl[tid] = b_ws[s * 512 + tid];

  __syncthreads();

#pragma unroll 1
  for (int it = 0; it < 2; ++it) {
    const int px0 = chunk * 1024 + it * 512 + wv * 64;

    // pack current x regs -> bf16 B-frags (used by IN and SHORT stages);
    // xr is then dead until the OUT stage re-issues next-iter loads
    bf16x8 xf[2][4];
#pragma unroll
    for (int nt = 0; nt < 2; ++nt) {
#pragma unroll
      for (int ks = 0; ks < 4; ++ks) {
        union { unsigned u[4]; bf16x8 v8; } uu;
#pragma unroll
        for (int j = 0; j < 4; ++j)
          uu.u[j] = pk2(xr[nt][ks][2 * j], xr[nt][ks][2 * j + 1]);
        xf[nt][ks] = uu.v8;
      }
    }

    bf16x8 hA[16], hB2[16];

    // ---- stage IN: h1 = relu(k_in @ x + b_in)   (M=128, K=64) -> hA
#pragma unroll
    for (int mt = 0; mt < 4; ++mt) {
      f32x16 a0 = bias_init(bl + 0, mt, lh);
      f32x16 a1 = a0;
#pragma unroll
      for (int ks = 0; ks < 4; ++ks) {
        const bf16x8 A = *(const bf16x8*)&wl[(mt * 4 + ks) * 512 + l * 8];
        a0 = MFMA32(A, xf[0][ks], a0);
        a1 = MFMA32(A, xf[1][ks], a1);
      }
      acc_to_bfrags(a0, a1, hA, mt);
    }

    // ---- stage MIDA: h2 = relu(k_mida @ h1 + b) (M=128, K=128) hA -> hB2
#pragma unroll
    for (int mt = 0; mt < 4; ++mt) {
      f32x16 a0 = bias_init(bl + 128, mt, lh);
      f32x16 a1 = a0;
#pragma unroll
      for (int ks = 0; ks < 8; ++ks) {
        const bf16x8 A = *(const bf16x8*)&wl[(16 + mt * 8 + ks) * 512 + l * 8];
        a0 = MFMA32(A, hA[ks * 2 + 0], a0);
        a1 = MFMA32(A, hA[ks * 2 + 1], a1);
      }
      acc_to_bfrags(a0, a1, hB2, mt);
    }

    // ---- stage MIDB: h3 = relu(k_midb @ h2 + b) (M=128, K=128) hB2 -> hA
#pragma unroll
    for (int mt = 0; mt < 4; ++mt) {
      f32x16 a0 = bias_init(bl + 256, mt, lh);
      f32x16 a1 = a0;
#pragma unroll
      for (int ks = 0; ks < 8; ++ks) {
        const bf16x8 A = *(const bf16x8*)&wl[(48 + mt * 8 + ks) * 512 + l * 8];
        a0 = MFMA32(A, hB2[ks * 2 + 0], a0);
        a1 = MFMA32(A, hB2[ks * 2 + 1], a1);
      }
      acc_to_bfrags(a0, a1, hA, mt);
    }

    // ---- stage OUT: out = k_out@h3 + k_short@x + b_out + b_short  (M=64)
    // issue next-iter x loads first: HBM latency hides under the OUT MFMAs
    if (it == 0) load_xr(1);
#pragma unroll
    for (int mt = 0; mt < 2; ++mt) {
      f32x16 a0 = bias_init(bl + 384, mt, lh);
      {
        const f32x16 bs = bias_init(bl + 448, mt, lh);
#pragma unroll
        for (int e = 0; e < 16; ++e) a0[e] += bs[e];
      }
      f32x16 a1 = a0;
#pragma unroll
      for (int ks = 0; ks < 4; ++ks) {  // shortcut: K=64, B = x frags
        const bf16x8 A = *(const bf16x8*)&wl[(96 + mt * 4 + ks) * 512 + l * 8];
        a0 = MFMA32(A, xf[0][ks], a0);
        a1 = MFMA32(A, xf[1][ks], a1);
      }
#pragma unroll
      for (int ks = 0; ks < 8; ++ks) {  // k_out: K=128, B = h3
        const bf16x8 A = *(const bf16x8*)&wl[(80 + mt * 8 + ks) * 512 + l * 8];
        a0 = MFMA32(A, hA[ks * 2 + 0], a0);
        a1 = MFMA32(A, hA[ks * 2 + 1], a1);
      }
#pragma unroll
      for (int g = 0; g < 4; ++g) {
#pragma unroll
        for (int q = 0; q < 4; ++q) {
          const int row = mt * 32 + 8 * g + 4 * lh + q;
          float* op = out + (size_t)(s * 64 + row) * 16384 + px0 + l31;
          op[0]  = a0[4 * g + q];
          op[32] = a1[4 * g + q];
        }
      }
    }
  }
}

// ---------------------------------------------------------------------------
extern "C" void kernel_launch(void* const* d_in, const int* in_sizes, int n_in,
                              void* d_out, int out_size, void* d_ws,
                              size_t ws_size, hipStream_t stream) {
  (void)in_sizes; (void)n_in; (void)out_size; (void)ws_size;
  const float* x   = (const float*)d_in[0];
  const float* lat = (const float*)d_in[1];
  const float* W   = (const float*)d_in[2];
  const float* b   = (const float*)d_in[3];
  unsigned short* w_ws = (unsigned short*)d_ws;
  float* b_ws = (float*)((char*)d_ws + WS_BOFF);
  unsigned short* ah_ws = (unsigned short*)((char*)d_ws + WS_AHOFF);
  unsigned short* al_ws = (unsigned short*)((char*)d_ws + WS_ALOFF);
  float* out = (float*)d_out;

  lat_prep<<<dim3(4), dim3(256), 0, stream>>>(lat, ah_ws, al_ws);
  hyper_gemm<<<dim3(840), dim3(256), 0, stream>>>(W, b, ah_ws, al_ws, w_ws, b_ws);
  dyn_conv<<<dim3(256), dim3(512), 0, stream>>>(x, w_ws, b_ws, out);
}

// Round 2
// 447.446 us; speedup vs baseline: 1.3422x; 1.3422x over previous
//
#include <hip/hip_runtime.h>
#include <cstdint>
#include <cstddef>

// ---------------------------------------------------------------------------
// DynaResidualBlock: hypernet GEMM (MFMA, hi/lo bf16 split = fp32-accurate)
//  -> per-sample 1x1 conv chain (bf16 MFMA)
//   FIN=64 FOUT=64 FH=128 LAT=512  B=16  H*W=16384
//   sizes = [8192,16384,16384,8192,4096,128,128,128,64,64], KTOT=53760
// ---------------------------------------------------------------------------

typedef short bf16x8 __attribute__((ext_vector_type(8)));   // 8 bf16 = 4 VGPRs
typedef float f32x4  __attribute__((ext_vector_type(4)));
typedef float f32x16 __attribute__((ext_vector_type(16)));  // MFMA 32x32 acc

#define DEVFN static __device__ __forceinline__

constexpr int WELEM      = 53248;           // bf16 weight elements per sample
constexpr size_t WS_WSHORTS = (size_t)WELEM;
constexpr size_t WS_WBYTES_TOT = (size_t)16 * WELEM * 2;     // 1,703,936
constexpr size_t WS_BOFF  = WS_WBYTES_TOT;                   // b_ws: 16*512 f32
constexpr size_t WS_AHOFF = WS_BOFF + 16 * 512 * 4;          // ah frags: 16 KB
constexpr size_t WS_ALOFF = WS_AHOFF + 16384;                // al frags: 16 KB

DEVFN unsigned bf16rne(float f) {
  unsigned u = __builtin_bit_cast(unsigned, f);
  return (u + 0x7fffu + ((u >> 16) & 1u)) >> 16;
}
DEVFN unsigned pk2(float lo, float hi) {
  return bf16rne(lo) | (bf16rne(hi) << 16);
}

// ---------------------------------------------------------------------------
// Kernel 0: lat -> hi/lo bf16 A-frags for mfma_16x16x32.
// frag element (s, lane l, j): A[m=l&15][k = s*32 + (l>>4)*8 + j]
// stored at ah_ws[(s*64+l)*8 + j]. 1024 (s,l) pairs.
// ---------------------------------------------------------------------------
__global__ __launch_bounds__(256) void lat_prep(
    const float* __restrict__ lat, unsigned short* __restrict__ ah_ws,
    unsigned short* __restrict__ al_ws) {
  const int id = blockIdx.x * 256 + threadIdx.x;  // 0..1023
  const int s = id >> 6, l = id & 63;
  const int m = l & 15, q = l >> 4;
  const float* ap = lat + m * 512 + s * 32 + q * 8;
  float f[8];
#pragma unroll
  for (int j = 0; j < 8; ++j) f[j] = ap[j];
  unsigned H[4], L[4];
#pragma unroll
  for (int p = 0; p < 4; ++p) {
    const unsigned u0 = __builtin_bit_cast(unsigned, f[2 * p]);
    const unsigned u1 = __builtin_bit_cast(unsigned, f[2 * p + 1]);
    const unsigned h0 = u0 & 0xFFFF0000u, h1 = u1 & 0xFFFF0000u;
    H[p] = (h0 >> 16) | h1;
    const float lo0 = f[2 * p] - __builtin_bit_cast(float, h0);
    const float lo1 = f[2 * p + 1] - __builtin_bit_cast(float, h1);
    L[p] = pk2(lo0, lo1);
  }
  *(uint4*)&ah_ws[(size_t)(s * 64 + l) * 8] = make_uint4(H[0], H[1], H[2], H[3]);
  *(uint4*)&al_ws[(size_t)(s * 64 + l) * 8] = make_uint4(L[0], L[1], L[2], L[3]);
}

// ---------------------------------------------------------------------------
// Kernel 1: ks = lat @ W.T + bias via MFMA 16x16x32 (hi/lo split, 3 mfma/step)
// One 16-column tile per wave; 3360 tiles = 840 blocks x 4 waves.
// Wave streams its 16 W rows (columns of ks) with an 8-step float4 ring
// (16 KB in flight per wave). Epilogue scatters to frag-layout bf16 ws.
// ---------------------------------------------------------------------------
#define MFMA16(A, B, C) __builtin_amdgcn_mfma_f32_16x16x32_bf16((A), (B), (C), 0, 0, 0)

__global__ __launch_bounds__(256, 2) void hyper_gemm(
    const float* __restrict__ W, const float* __restrict__ bias,
    const unsigned short* __restrict__ ah_ws,
    const unsigned short* __restrict__ al_ws,
    unsigned short* __restrict__ w_ws, float* __restrict__ b_ws) {
  const int tid = threadIdx.x;
  const int wv = tid >> 6;
  const int l = tid & 63;
  const int q = l >> 4;
  const int g = blockIdx.x * 4 + wv;  // tile id 0..3359
  const int n0 = g * 16;
  const int n = n0 + (l & 15);

  // A frags (shared by all waves; L2-hot)
  bf16x8 Ah[16], Al[16];
#pragma unroll
  for (int s = 0; s < 16; ++s) {
    Ah[s] = *(const bf16x8*)&ah_ws[(size_t)(s * 64 + l) * 8];
    Al[s] = *(const bf16x8*)&al_ws[(size_t)(s * 64 + l) * 8];
  }

  // B stream: lane reads W[n][s*32 + q*8 .. +8]
  const float* bp = W + (size_t)n * 512 + q * 8;
  float4 ld[8][2];
#pragma unroll
  for (int s = 0; s < 8; ++s) {
    ld[s][0] = *(const float4*)(bp + s * 32);
    ld[s][1] = *(const float4*)(bp + s * 32 + 4);
  }

  f32x4 acc = {0.f, 0.f, 0.f, 0.f};
#pragma unroll
  for (int s = 0; s < 16; ++s) {
    const float4 b0 = ld[s & 7][0];
    const float4 b1 = ld[s & 7][1];
    if (s < 8) {
      ld[s][0] = *(const float4*)(bp + (s + 8) * 32);
      ld[s][1] = *(const float4*)(bp + (s + 8) * 32 + 4);
    }
    const float f[8] = {b0.x, b0.y, b0.z, b0.w, b1.x, b1.y, b1.z, b1.w};
    union { unsigned u[4]; bf16x8 v; } BH, BL;
#pragma unroll
    for (int p = 0; p < 4; ++p) {
      const unsigned u0 = __builtin_bit_cast(unsigned, f[2 * p]);
      const unsigned u1 = __builtin_bit_cast(unsigned, f[2 * p + 1]);
      const unsigned h0 = u0 & 0xFFFF0000u, h1 = u1 & 0xFFFF0000u;
      BH.u[p] = (h0 >> 16) | h1;
      const float lo0 = f[2 * p] - __builtin_bit_cast(float, h0);
      const float lo1 = f[2 * p + 1] - __builtin_bit_cast(float, h1);
      BL.u[p] = pk2(lo0, lo1);
    }
    acc = MFMA16(Ah[s], BH.v, acc);
    acc = MFMA16(Ah[s], BL.v, acc);
    acc = MFMA16(Al[s], BH.v, acc);
  }

  // epilogue: lane holds column n, samples b = q*4 + r  (D: col=l&15, row=q*4+r)
  const float bv = bias[n];
  if (n0 >= 53248) {  // conv biases: fp32, per-sample contiguous [512]
    const int j = n - 53248;
#pragma unroll
    for (int r = 0; r < 4; ++r) b_ws[(q * 4 + r) * 512 + j] = acc[r] + bv;
    return;
  }
  int fragbase, off, kbits;
  float scale;
  if (n < 8192)       { fragbase = 0;  off = 0;     kbits = 6; scale = 0.08838834764831845f; }
  else if (n < 24576) { fragbase = 16; off = 8192;  kbits = 7; scale = 0.08838834764831845f; }
  else if (n < 40960) { fragbase = 48; off = 24576; kbits = 7; scale = 0.08838834764831845f; }
  else if (n < 49152) { fragbase = 80; off = 40960; kbits = 7; scale = 0.125f; }
  else                { fragbase = 96; off = 49152; kbits = 6; scale = 0.125f; }
  const int r0 = n - off;
  const int m = r0 >> kbits;
  const int k = r0 & ((1 << kbits) - 1);
  const int mt = m >> 5, ks = k >> 4;
  const int lane = (m & 31) + 32 * ((k >> 3) & 1);
  const int j = k & 7;
  const int frag = fragbase + mt * (1 << (kbits - 4)) + ks;
  const size_t eoff = (size_t)frag * 512 + lane * 8 + j;  // in shorts
#pragma unroll
  for (int r = 0; r < 4; ++r) {
    const float v = (acc[r] + bv) * scale;
    w_ws[(size_t)(q * 4 + r) * WS_WSHORTS + eoff] = (unsigned short)bf16rne(v);
  }
}

// ---------------------------------------------------------------------------
// Kernel 2: per-sample conv chain, v3.
// 256 blocks (sample = blk>>4, chunk = blk&15), 4 waves (256 thr,
// __launch_bounds__(256,1) => full 512-VGPR budget per wave; v2's 8-wave
// variant capped VGPRs at 128 and spilled ~900 MB to scratch — FETCH/WRITE
// counters showed it directly). Each wave owns 64 pixels/iter, 4 iters.
// ALL weight A-frags staged in LDS (104 frags = 106.5 KB; 1 block/CU).
// h handoff between stages is fully in-register: C-frag acc -> pk2 bf16
// pairs -> permlane32_swap half-exchange -> B-frags (no LDS round trip;
// v2 measured SQ_LDS_BANK_CONFLICT == 0 with this scheme, and it refchecks).
//   C layout (32x32): col=l&31, row=(reg&3)+8*(reg>>2)+4*(l>>5)
//   B layout (32x32x16): n=l&31, k=8*(l>>5)+j
//   => with P[G][w]=pk2(acc[4G+2w],acc[4G+2w+1]),
//      r = permlane32_swap(P[2e][w], P[2e+1][w]) gives
//      r[0]={a.lo,b.lo} = B word j=(2w,2w+1), r[1]={a.hi,b.hi} = j=(2w+4,2w+5)
//      of frag ks=2*mt+e.
// Next-iter x loads issued right after the xf pack (v1's proven schedule):
// HBM latency hides under all four MFMA stages; 4-wave budget absorbs the
// 64 live xr regs alongside hA/hB2.
// ---------------------------------------------------------------------------

DEVFN f32x16 bias_init(const float* bl, int mt, int lh) {
  f32x16 a;
#pragma unroll
  for (int g = 0; g < 4; ++g) {
    const float4 bv = *(const float4*)&bl[mt * 32 + 8 * g + 4 * lh];
    a[4 * g + 0] = bv.x; a[4 * g + 1] = bv.y;
    a[4 * g + 2] = bv.z; a[4 * g + 3] = bv.w;
  }
  return a;
}

// acc (nt=0,nt=1) of output-channel tile mt -> relu -> 4 B-frags into
// h[(2*mt+e)*2 + nt]  (frag ks=2*mt+e covers channels 16ks..16ks+15)
DEVFN void acc_to_bfrags(const f32x16& a0, const f32x16& a1, bf16x8* h, int mt) {
  unsigned P0[4][2], P1[4][2];  // [G][w]
#pragma unroll
  for (int g = 0; g < 4; ++g) {
    P0[g][0] = pk2(fmaxf(a0[4 * g + 0], 0.f), fmaxf(a0[4 * g + 1], 0.f));
    P0[g][1] = pk2(fmaxf(a0[4 * g + 2], 0.f), fmaxf(a0[4 * g + 3], 0.f));
    P1[g][0] = pk2(fmaxf(a1[4 * g + 0], 0.f), fmaxf(a1[4 * g + 1], 0.f));
    P1[g][1] = pk2(fmaxf(a1[4 * g + 2], 0.f), fmaxf(a1[4 * g + 3], 0.f));
  }
#pragma unroll
  for (int e = 0; e < 2; ++e) {
    auto r0 = __builtin_amdgcn_permlane32_swap(P0[2 * e][0], P0[2 * e + 1][0], false, false);
    auto r1 = __builtin_amdgcn_permlane32_swap(P0[2 * e][1], P0[2 * e + 1][1], false, false);
    union { unsigned u[4]; bf16x8 v; } F0;
    F0.u[0] = r0[0]; F0.u[1] = r1[0]; F0.u[2] = r0[1]; F0.u[3] = r1[1];
    h[(2 * mt + e) * 2 + 0] = F0.v;
    auto q0 = __builtin_amdgcn_permlane32_swap(P1[2 * e][0], P1[2 * e + 1][0], false, false);
    auto q1 = __builtin_amdgcn_permlane32_swap(P1[2 * e][1], P1[2 * e + 1][1], false, false);
    union { unsigned u[4]; bf16x8 v; } F1;
    F1.u[0] = q0[0]; F1.u[1] = q1[0]; F1.u[2] = q0[1]; F1.u[3] = q1[1];
    h[(2 * mt + e) * 2 + 1] = F1.v;
  }
}

#define MFMA32(A, B, C) __builtin_amdgcn_mfma_f32_32x32x16_bf16((A), (B), (C), 0, 0, 0)

__global__ __launch_bounds__(256, 1) void dyn_conv(
    const float* __restrict__ x, const unsigned short* __restrict__ w_ws,
    const float* __restrict__ b_ws, float* __restrict__ out) {
  // LDS frag order = w_ws layout: in[0..16) mida[16..48) midb[48..80)
  //                               out[80..96) short[96..104)
  __shared__ short wl[104 * 512];  // 106496 B
  __shared__ float bl[512];        //   2048 B

  const int s = blockIdx.x >> 4;
  const int chunk = blockIdx.x & 15;
  const int tid = threadIdx.x;
  const int wv = tid >> 6;       // 0..3
  const int l = tid & 63;
  const int l31 = l & 31;
  const int lh = l >> 5;

  const unsigned short* wbase = w_ws + (size_t)s * WS_WSHORTS;
  const float* xbase = x + (size_t)(s * 64) * 16384;

  float xr[2][4][8];
  auto load_xr = [&](int it2) {
    const int px0 = chunk * 1024 + it2 * 256 + wv * 64;
#pragma unroll
    for (int nt = 0; nt < 2; ++nt) {
#pragma unroll
      for (int ks = 0; ks < 4; ++ks) {
        const float* xp =
            xbase + (size_t)(ks * 16 + lh * 8) * 16384 + px0 + nt * 32 + l31;
#pragma unroll
        for (int j = 0; j < 8; ++j) xr[nt][ks][j] = xp[(size_t)j * 16384];
      }
    }
  };
  // iter-0 x loads first: HBM latency overlaps the weight staging below
  load_xr(0);

  // stage ALL weights -> LDS (w_ws frag layout is contiguous; copy verbatim)
  for (int f = wv; f < 104; f += 4)
    *(int4*)&wl[f * 512 + l * 8] = *(const int4*)&wbase[(size_t)f * 512 + l * 8];
  bl[tid] = b_ws[s * 512 + tid];
  bl[tid + 256] = b_ws[s * 512 + tid + 256];

  __syncthreads();

#pragma unroll 1
  for (int it = 0; it < 4; ++it) {
    const int px0 = chunk * 1024 + it * 256 + wv * 64;

    // pack current x regs -> bf16 B-frags (used by IN and SHORT stages)
    bf16x8 xf[2][4];
#pragma unroll
    for (int nt = 0; nt < 2; ++nt) {
#pragma unroll
      for (int ks = 0; ks < 4; ++ks) {
        union { unsigned u[4]; bf16x8 v8; } uu;
#pragma unroll
        for (int j = 0; j < 4; ++j)
          uu.u[j] = pk2(xr[nt][ks][2 * j], xr[nt][ks][2 * j + 1]);
        xf[nt][ks] = uu.v8;
      }
    }
    // prefetch next iteration's x; latency overlaps all four MFMA stages
    if (it < 3) load_xr(it + 1);

    bf16x8 hA[16], hB2[16];

    // ---- stage IN: h1 = relu(k_in @ x + b_in)   (M=128, K=64) -> hA
#pragma unroll
    for (int mt = 0; mt < 4; ++mt) {
      f32x16 a0 = bias_init(bl + 0, mt, lh);
      f32x16 a1 = a0;
#pragma unroll
      for (int ks = 0; ks < 4; ++ks) {
        const bf16x8 A = *(const bf16x8*)&wl[(mt * 4 + ks) * 512 + l * 8];
        a0 = MFMA32(A, xf[0][ks], a0);
        a1 = MFMA32(A, xf[1][ks], a1);
      }
      acc_to_bfrags(a0, a1, hA, mt);
    }

    // ---- stage MIDA: h2 = relu(k_mida @ h1 + b) (M=128, K=128) hA -> hB2
#pragma unroll
    for (int mt = 0; mt < 4; ++mt) {
      f32x16 a0 = bias_init(bl + 128, mt, lh);
      f32x16 a1 = a0;
#pragma unroll
      for (int ks = 0; ks < 8; ++ks) {
        const bf16x8 A = *(const bf16x8*)&wl[(16 + mt * 8 + ks) * 512 + l * 8];
        a0 = MFMA32(A, hA[ks * 2 + 0], a0);
        a1 = MFMA32(A, hA[ks * 2 + 1], a1);
      }
      acc_to_bfrags(a0, a1, hB2, mt);
    }

    // ---- stage MIDB: h3 = relu(k_midb @ h2 + b) (M=128, K=128) hB2 -> hA
#pragma unroll
    for (int mt = 0; mt < 4; ++mt) {
      f32x16 a0 = bias_init(bl + 256, mt, lh);
      f32x16 a1 = a0;
#pragma unroll
      for (int ks = 0; ks < 8; ++ks) {
        const bf16x8 A = *(const bf16x8*)&wl[(48 + mt * 8 + ks) * 512 + l * 8];
        a0 = MFMA32(A, hB2[ks * 2 + 0], a0);
        a1 = MFMA32(A, hB2[ks * 2 + 1], a1);
      }
      acc_to_bfrags(a0, a1, hA, mt);
    }

    // ---- stage OUT: out = k_out@h3 + k_short@x + b_out + b_short  (M=64)
#pragma unroll
    for (int mt = 0; mt < 2; ++mt) {
      f32x16 a0 = bias_init(bl + 384, mt, lh);
      {
        const f32x16 bs = bias_init(bl + 448, mt, lh);
#pragma unroll
        for (int e = 0; e < 16; ++e) a0[e] += bs[e];
      }
      f32x16 a1 = a0;
#pragma unroll
      for (int ks = 0; ks < 4; ++ks) {  // shortcut: K=64, B = x frags
        const bf16x8 A = *(const bf16x8*)&wl[(96 + mt * 4 + ks) * 512 + l * 8];
        a0 = MFMA32(A, xf[0][ks], a0);
        a1 = MFMA32(A, xf[1][ks], a1);
      }
#pragma unroll
      for (int ks = 0; ks < 8; ++ks) {  // k_out: K=128, B = h3
        const bf16x8 A = *(const bf16x8*)&wl[(80 + mt * 8 + ks) * 512 + l * 8];
        a0 = MFMA32(A, hA[ks * 2 + 0], a0);
        a1 = MFMA32(A, hA[ks * 2 + 1], a1);
      }
#pragma unroll
      for (int g = 0; g < 4; ++g) {
#pragma unroll
        for (int q = 0; q < 4; ++q) {
          const int row = mt * 32 + 8 * g + 4 * lh + q;
          float* op = out + (size_t)(s * 64 + row) * 16384 + px0 + l31;
          op[0]  = a0[4 * g + q];
          op[32] = a1[4 * g + q];
        }
      }
    }
  }
}

// ---------------------------------------------------------------------------
extern "C" void kernel_launch(void* const* d_in, const int* in_sizes, int n_in,
                              void* d_out, int out_size, void* d_ws,
                              size_t ws_size, hipStream_t stream) {
  (void)in_sizes; (void)n_in; (void)out_size; (void)ws_size;
  const float* x   = (const float*)d_in[0];
  const float* lat = (const float*)d_in[1];
  const float* W   = (const float*)d_in[2];
  const float* b   = (const float*)d_in[3];
  unsigned short* w_ws = (unsigned short*)d_ws;
  float* b_ws = (float*)((char*)d_ws + WS_BOFF);
  unsigned short* ah_ws = (unsigned short*)((char*)d_ws + WS_AHOFF);
  unsigned short* al_ws = (unsigned short*)((char*)d_ws + WS_ALOFF);
  float* out = (float*)d_out;

  lat_prep<<<dim3(4), dim3(256), 0, stream>>>(lat, ah_ws, al_ws);
  hyper_gemm<<<dim3(840), dim3(256), 0, stream>>>(W, b, ah_ws, al_ws, w_ws, b_ws);
  dyn_conv<<<dim3(256), dim3(256), 0, stream>>>(x, w_ws, b_ws, out);
}